// Round 4
// baseline (2850.097 us; speedup 1.0000x reference)
//
#include <hip/hip_runtime.h>

// LSTMFromEmbeddings: B=128, T=1024, E=256, H=256, C=2, bidirectional + meanpool + linear.
//
// R4: latency-optimized recurrence with raw barriers (no vmcnt drains in loop).
//  rec: 64 persistent wgs = 16 groups (2 dir x 8 batch-blocks of 16) x 4 members
//       (64 hidden units each); weights in registers (128 VGPR/lane).
//       Per step: hh MFMA -> gates -> ew -> publish (agent-scope tagged 64b words,
//       fire-and-forget) -> poll-issue -> stage x_{t+1} -> xg MFMA (hides poll rt)
//       -> poll-check -> stage h -> raw barrier (lgkmcnt only; global ops never
//       drained on the critical path).
//  head: out = (hsum/1024) @ W_lin^T + b_lin.

#define B_ 128
#define T_ 1024
#define E_ 256
#define H_ 256

typedef short short8 __attribute__((ext_vector_type(8)));
typedef float f32x4 __attribute__((ext_vector_type(4)));

__device__ __forceinline__ unsigned short f2bf(float f) {
  unsigned u = __builtin_bit_cast(unsigned, f);
  u += 0x7fffu + ((u >> 16) & 1u);  // RNE
  return (unsigned short)(u >> 16);
}
__device__ __forceinline__ f32x4 mfma16(short8 a, short8 b, f32x4 c) {
  return __builtin_amdgcn_mfma_f32_16x16x32_bf16(a, b, c, 0, 0, 0);
}
__device__ __forceinline__ float sigmf(float x) { return 1.0f / (1.0f + __expf(-x)); }
__device__ __forceinline__ float tanhfast(float x) { return 2.0f / (1.0f + __expf(-2.0f * x)) - 1.0f; }

__device__ __forceinline__ short8 cvt8(f32x4 v0, f32x4 v1) {
  short8 o;
  o[0] = (short)f2bf(v0[0]); o[1] = (short)f2bf(v0[1]);
  o[2] = (short)f2bf(v0[2]); o[3] = (short)f2bf(v0[3]);
  o[4] = (short)f2bf(v1[0]); o[5] = (short)f2bf(v1[1]);
  o[6] = (short)f2bf(v1[2]); o[7] = (short)f2bf(v1[3]);
  return o;
}

// raw barrier: waits LDS ops only; global loads/stores stay in flight.
__device__ __forceinline__ void bar_lds() {
  asm volatile("s_waitcnt lgkmcnt(0)" ::: "memory");
  __builtin_amdgcn_s_barrier();
}

// ---------------- rec: fused projection + recurrence, weights-in-registers ---
// grid 64, 512 threads. group g = bid & 15, member m = bid >> 4 (members co-XCD:
// bids {g, g+16, g+32, g+48} are congruent mod 8). Member m owns units [m*64, m*64+64).
__global__ __launch_bounds__(512, 1) void rec_kernel(
    const float* __restrict__ x, const float* __restrict__ mask,
    const float* __restrict__ WihF, const float* __restrict__ WhhF,
    const float* __restrict__ bF, const float* __restrict__ WihB,
    const float* __restrict__ WhhB, const float* __restrict__ bB,
    unsigned long long* __restrict__ Hbuf, float* __restrict__ hsum) {
  __shared__ __align__(16) short XS[16 * 256];     // x_t stage bf16 swizzled (8KB)
  __shared__ __align__(16) short HS[16 * 256];     // h_t stage bf16 swizzled (8KB)
  __shared__ __align__(16) float gatesL[16 * 260]; // gates fp32, +4 pad (16.6KB)

  const int bid = blockIdx.x;
  const int g = bid & 15, m = bid >> 4;
  const int d = g >> 3, bblk = g & 7;
  const int tid = threadIdx.x;
  const int w = tid >> 6, l = tid & 63, l15 = l & 15, l4 = l >> 4;
  const int sr = tid >> 5, sc = tid & 31;  // stage/elementwise: batch row, chunk
  const int ej2 = sc * 2;                  // local unit base (2 units/thread)
  const int gb = bblk * 16 + sr;           // global batch

  const float* Wih = d ? WihB : WihF;
  const float* Whh = d ? WhhB : WhhF;
  const float* bias = d ? bB : bF;

  // ---- weight fragments -> registers (one-time) ----
  short8 wi[2][8], wh[2][8];
#pragma unroll
  for (int i = 0; i < 2; ++i) {
    int cp = (2 * w + i) * 16 + l15;
    int gate = cp >> 6, ul = cp & 63;
    size_t nat = (size_t)(gate * 256 + m * 64 + ul);
#pragma unroll
    for (int kb = 0; kb < 8; ++kb) {
      const f32x4* pi = (const f32x4*)(Wih + nat * E_ + kb * 32 + l4 * 8);
      wi[i][kb] = cvt8(pi[0], pi[1]);
      const f32x4* ph = (const f32x4*)(Whh + nat * H_ + kb * 32 + l4 * 8);
      wh[i][kb] = cvt8(ph[0], ph[1]);
    }
  }

  const int ub = m * 64 + ej2;
  float bI0 = bias[ub], bI1 = bias[ub + 1];
  float bF0 = bias[256 + ub], bF1 = bias[256 + ub + 1];
  float bG0 = bias[512 + ub], bG1 = bias[512 + ub + 1];
  float bO0 = bias[768 + ub], bO1 = bias[768 + ub + 1];

  // ---- prologue: stage x_0, acc = xg_0 ----
  {
    int ts = d ? (T_ - 1) : 0;
    const f32x4* px = (const f32x4*)(x + ((size_t)gb * T_ + ts) * E_ + sc * 8);
    float mk = mask[(size_t)gb * T_ + ts];
    ((short8*)XS)[sr * 32 + (sc ^ (sr & 7))] = cvt8(px[0] * mk, px[1] * mk);
  }
  __syncthreads();
  f32x4 acc[2] = {}, accB[2] = {};
#pragma unroll
  for (int kp = 0; kp < 4; ++kp) {
    short8 a0 = ((short8*)XS)[l15 * 32 + ((kp * 8 + l4) ^ (l15 & 7))];
    acc[0] = mfma16(a0, wi[0][2 * kp], acc[0]);
    acc[1] = mfma16(a0, wi[1][2 * kp], acc[1]);
    short8 a1 = ((short8*)XS)[l15 * 32 + ((kp * 8 + 4 + l4) ^ (l15 & 7))];
    accB[0] = mfma16(a1, wi[0][2 * kp + 1], accB[0]);
    accB[1] = mfma16(a1, wi[1][2 * kp + 1], accB[1]);
  }
  __syncthreads();  // XS consumed by all waves before loop overwrites it

  float cs0 = 0.f, cs1 = 0.f, hs0 = 0.f, hs1 = 0.f;

  for (int t = 0; t < T_; ++t) {
    // x prefetch for t+1: issued here, consumed ~3 phases later; never force-drained
    f32x4 xv0, xv1;
    float mk = 0.f;
    const bool more = (t + 1 < T_);
    if (more) {
      int ts = d ? (T_ - 2 - t) : (t + 1);
      const f32x4* px = (const f32x4*)(x + ((size_t)gb * T_ + ts) * E_ + sc * 8);
      xv0 = px[0];
      xv1 = px[1];
      mk = mask[(size_t)gb * T_ + ts];
    }

    // hh product into acc (acc holds xg_t)
    if (t > 0) {
#pragma unroll
      for (int kp = 0; kp < 4; ++kp) {
        short8 a0 = ((short8*)HS)[l15 * 32 + ((kp * 8 + l4) ^ (l15 & 7))];
        acc[0] = mfma16(a0, wh[0][2 * kp], acc[0]);
        acc[1] = mfma16(a0, wh[1][2 * kp], acc[1]);
        short8 a1 = ((short8*)HS)[l15 * 32 + ((kp * 8 + 4 + l4) ^ (l15 & 7))];
        accB[0] = mfma16(a1, wh[0][2 * kp + 1], accB[0]);
        accB[1] = mfma16(a1, wh[1][2 * kp + 1], accB[1]);
      }
    }

    // gates -> LDS. D layout: row(batch)=l4*4+r, col'=(2w+i)*16+l15
#pragma unroll
    for (int i = 0; i < 2; ++i)
#pragma unroll
      for (int r = 0; r < 4; ++r)
        gatesL[(l4 * 4 + r) * 260 + (2 * w + i) * 16 + l15] = acc[i][r] + accB[i][r];
    bar_lds();  // (1) gates visible

    // fp32 LSTM elementwise: 2 units (ej2, ej2+1), batch sr
    float gi0 = gatesL[sr * 260 + ej2] + bI0;
    float gf0 = gatesL[sr * 260 + 64 + ej2] + bF0;
    float gg0 = gatesL[sr * 260 + 128 + ej2] + bG0;
    float go0 = gatesL[sr * 260 + 192 + ej2] + bO0;
    float gi1 = gatesL[sr * 260 + ej2 + 1] + bI1;
    float gf1 = gatesL[sr * 260 + 64 + ej2 + 1] + bF1;
    float gg1 = gatesL[sr * 260 + 128 + ej2 + 1] + bG1;
    float go1 = gatesL[sr * 260 + 192 + ej2 + 1] + bO1;
    cs0 = sigmf(gf0) * cs0 + sigmf(gi0) * tanhfast(gg0);
    cs1 = sigmf(gf1) * cs1 + sigmf(gi1) * tanhfast(gg1);
    float h0 = sigmf(go0) * tanhfast(cs0);
    float h1 = sigmf(go1) * tanhfast(cs1);
    hs0 += h0;
    hs1 += h1;

    if (more) {
      const unsigned tag = (unsigned)(t + 1);
      const size_t base = ((size_t)g * 2 + (tag & 1)) * 16;  // [grp][parity][16b][128w]

      // publish own h slice ASAP (fire-and-forget; ack drains in background)
      unsigned payload = (unsigned)f2bf(h0) | ((unsigned)f2bf(h1) << 16);
      unsigned long long word = (((unsigned long long)tag) << 32) | payload;
      __hip_atomic_store(&Hbuf[(base + sr) * 128 + m * 32 + sc], word,
                         __ATOMIC_RELAXED, __HIP_MEMORY_SCOPE_AGENT);
      asm volatile("" ::: "memory");  // publish must not sink below the poll loop

      // poll-issue: first attempt overlaps XS stage + xg MFMA
      const unsigned long long* rp = &Hbuf[(base + sr) * 128 + sc * 4];
      unsigned long long vv[4];
#pragma unroll
      for (int j = 0; j < 4; ++j)
        vv[j] = __hip_atomic_load(&rp[j], __ATOMIC_RELAXED, __HIP_MEMORY_SCOPE_AGENT);
      asm volatile("" ::: "memory");

      // stage x_{t+1} (waits only this thread's x load)
      ((short8*)XS)[sr * 32 + (sc ^ (sr & 7))] = cvt8(xv0 * mk, xv1 * mk);
      bar_lds();  // (2) XS visible; gatesL fully read

      // acc = xg_{t+1}
      acc[0] = (f32x4){0.f, 0.f, 0.f, 0.f};
      acc[1] = (f32x4){0.f, 0.f, 0.f, 0.f};
      accB[0] = (f32x4){0.f, 0.f, 0.f, 0.f};
      accB[1] = (f32x4){0.f, 0.f, 0.f, 0.f};
#pragma unroll
      for (int kp = 0; kp < 4; ++kp) {
        short8 a0 = ((short8*)XS)[l15 * 32 + ((kp * 8 + l4) ^ (l15 & 7))];
        acc[0] = mfma16(a0, wi[0][2 * kp], acc[0]);
        acc[1] = mfma16(a0, wi[1][2 * kp], acc[1]);
        short8 a1 = ((short8*)XS)[l15 * 32 + ((kp * 8 + 4 + l4) ^ (l15 & 7))];
        accB[0] = mfma16(a1, wi[0][2 * kp + 1], accB[0]);
        accB[1] = mfma16(a1, wi[1][2 * kp + 1], accB[1]);
      }

      // poll-check: retry any stale words
#pragma unroll
      for (int j = 0; j < 4; ++j)
        while ((unsigned)(vv[j] >> 32) != tag)
          vv[j] = __hip_atomic_load(&rp[j], __ATOMIC_RELAXED, __HIP_MEMORY_SCOPE_AGENT);
      short8 hv;
#pragma unroll
      for (int j = 0; j < 4; ++j) {
        hv[2 * j] = (short)(unsigned short)(vv[j] & 0xffffu);
        hv[2 * j + 1] = (short)(unsigned short)((vv[j] >> 16) & 0xffffu);
      }
      ((short8*)HS)[sr * 32 + (sc ^ (sr & 7))] = hv;
      bar_lds();  // (3) HS visible; XS fully read
    }
  }

  hsum[((size_t)d * B_ + gb) * H_ + ub] = hs0;
  hsum[((size_t)d * B_ + gb) * H_ + ub + 1] = hs1;
}

// ---------------- head: linear ----------------------------------------------
__global__ __launch_bounds__(256, 1) void head_kernel(
    const float* __restrict__ hsum, const float* __restrict__ Wlin,
    const float* __restrict__ blin, float* __restrict__ out) {
  int tid = threadIdx.x;  // 256 = 128 b x 2 c
  int b = tid >> 1, c = tid & 1;
  const f32x4* hf = (const f32x4*)(hsum + (size_t)b * H_);
  const f32x4* hbk = (const f32x4*)(hsum + (size_t)B_ * H_ + (size_t)b * H_);
  const f32x4* wl = (const f32x4*)(Wlin + (size_t)c * 512);
  float s = 0.f;
  for (int j = 0; j < 64; ++j) {
    f32x4 a = hf[j], ww = wl[j];
    s += a[0] * ww[0] + a[1] * ww[1] + a[2] * ww[2] + a[3] * ww[3];
  }
  for (int j = 0; j < 64; ++j) {
    f32x4 a = hbk[j], ww = wl[64 + j];
    s += a[0] * ww[0] + a[1] * ww[1] + a[2] * ww[2] + a[3] * ww[3];
  }
  out[tid] = s * (1.0f / 1024.0f) + blin[c];
}

// ---------------- launch -----------------------------------------------------
extern "C" void kernel_launch(void* const* d_in, const int* in_sizes, int n_in,
                              void* d_out, int out_size, void* d_ws, size_t ws_size,
                              hipStream_t stream) {
  const float* emb = (const float*)d_in[0];
  const float* mask = (const float*)d_in[1];
  const float* Wih_f = (const float*)d_in[2];
  const float* Whh_f = (const float*)d_in[3];
  const float* b_f = (const float*)d_in[4];
  const float* Wih_b = (const float*)d_in[5];
  const float* Whh_b = (const float*)d_in[6];
  const float* b_b = (const float*)d_in[7];
  const float* Wlin = (const float*)d_in[8];
  const float* blin = (const float*)d_in[9];
  float* out = (float*)d_out;

  // Hbuf: [16 groups][2 parity][16 batches][128 unit-pair words] x 8B = 512 KiB
  const size_t HBUF_BYTES = (size_t)16 * 2 * 16 * 128 * 8;
  const size_t HSUM_BYTES = (size_t)2 * B_ * H_ * 4;  // 256 KiB
  if (ws_size < HBUF_BYTES + HSUM_BYTES) return;

  char* ws = (char*)d_ws;
  unsigned long long* Hbuf = (unsigned long long*)ws;
  float* hsum = (float*)(ws + HBUF_BYTES);

  hipMemsetAsync(Hbuf, 0, HBUF_BYTES, stream);  // tags start at 1; replay-safe
  rec_kernel<<<64, 512, 0, stream>>>(emb, mask, Wih_f, Whh_f, b_f,
                                     Wih_b, Whh_b, b_b, Hbuf, hsum);
  head_kernel<<<1, 256, 0, stream>>>(hsum, Wlin, blin, out);
}

// Round 5
// 2720.156 us; speedup vs baseline: 1.0478x; 1.0478x over previous
//
#include <hip/hip_runtime.h>

// LSTMFromEmbeddings: B=128, T=1024, E=256, H=256, C=2, bidirectional + meanpool + linear.
//
// R5: R4 structure (raw lgkm-only barriers, early publish, early poll-issue) with the
// poll retry fixed to PARALLEL rounds (re-issue all stale words, one wait per round)
// instead of 4 serial dependent L3 round trips.
//  rec: 64 persistent wgs = 16 groups (2 dir x 8 batch-blocks of 16) x 4 members
//       (64 hidden units each); weights in registers (128 VGPR/lane).
//  head: out = (hsum/1024) @ W_lin^T + b_lin.

#define B_ 128
#define T_ 1024
#define E_ 256
#define H_ 256

typedef short short8 __attribute__((ext_vector_type(8)));
typedef float f32x4 __attribute__((ext_vector_type(4)));

__device__ __forceinline__ unsigned short f2bf(float f) {
  unsigned u = __builtin_bit_cast(unsigned, f);
  u += 0x7fffu + ((u >> 16) & 1u);  // RNE
  return (unsigned short)(u >> 16);
}
__device__ __forceinline__ f32x4 mfma16(short8 a, short8 b, f32x4 c) {
  return __builtin_amdgcn_mfma_f32_16x16x32_bf16(a, b, c, 0, 0, 0);
}
__device__ __forceinline__ float sigmf(float x) { return 1.0f / (1.0f + __expf(-x)); }
__device__ __forceinline__ float tanhfast(float x) { return 2.0f / (1.0f + __expf(-2.0f * x)) - 1.0f; }

__device__ __forceinline__ short8 cvt8(f32x4 v0, f32x4 v1) {
  short8 o;
  o[0] = (short)f2bf(v0[0]); o[1] = (short)f2bf(v0[1]);
  o[2] = (short)f2bf(v0[2]); o[3] = (short)f2bf(v0[3]);
  o[4] = (short)f2bf(v1[0]); o[5] = (short)f2bf(v1[1]);
  o[6] = (short)f2bf(v1[2]); o[7] = (short)f2bf(v1[3]);
  return o;
}

// raw barrier: waits LDS ops only; global loads/stores stay in flight.
__device__ __forceinline__ void bar_lds() {
  asm volatile("s_waitcnt lgkmcnt(0)" ::: "memory");
  __builtin_amdgcn_s_barrier();
}

// ---------------- rec: fused projection + recurrence, weights-in-registers ---
// grid 64, 512 threads. group g = bid & 15, member m = bid >> 4 (members co-XCD
// heuristic: bids congruent mod 8). Member m owns units [m*64, m*64+64).
__global__ __launch_bounds__(512, 1) void rec_kernel(
    const float* __restrict__ x, const float* __restrict__ mask,
    const float* __restrict__ WihF, const float* __restrict__ WhhF,
    const float* __restrict__ bF, const float* __restrict__ WihB,
    const float* __restrict__ WhhB, const float* __restrict__ bB,
    unsigned long long* __restrict__ Hbuf, float* __restrict__ hsum) {
  __shared__ __align__(16) short XS[16 * 256];     // x_t stage bf16 swizzled (8KB)
  __shared__ __align__(16) short HS[16 * 256];     // h_t stage bf16 swizzled (8KB)
  __shared__ __align__(16) float gatesL[16 * 260]; // gates fp32, +4 pad (16.6KB)

  const int bid = blockIdx.x;
  const int g = bid & 15, m = bid >> 4;
  const int d = g >> 3, bblk = g & 7;
  const int tid = threadIdx.x;
  const int w = tid >> 6, l = tid & 63, l15 = l & 15, l4 = l >> 4;
  const int sr = tid >> 5, sc = tid & 31;  // stage/elementwise: batch row, chunk
  const int ej2 = sc * 2;                  // local unit base (2 units/thread)
  const int gb = bblk * 16 + sr;           // global batch

  const float* Wih = d ? WihB : WihF;
  const float* Whh = d ? WhhB : WhhF;
  const float* bias = d ? bB : bF;

  // ---- weight fragments -> registers (one-time) ----
  short8 wi[2][8], wh[2][8];
#pragma unroll
  for (int i = 0; i < 2; ++i) {
    int cp = (2 * w + i) * 16 + l15;
    int gate = cp >> 6, ul = cp & 63;
    size_t nat = (size_t)(gate * 256 + m * 64 + ul);
#pragma unroll
    for (int kb = 0; kb < 8; ++kb) {
      const f32x4* pi = (const f32x4*)(Wih + nat * E_ + kb * 32 + l4 * 8);
      wi[i][kb] = cvt8(pi[0], pi[1]);
      const f32x4* ph = (const f32x4*)(Whh + nat * H_ + kb * 32 + l4 * 8);
      wh[i][kb] = cvt8(ph[0], ph[1]);
    }
  }

  const int ub = m * 64 + ej2;
  float bI0 = bias[ub], bI1 = bias[ub + 1];
  float bF0 = bias[256 + ub], bF1 = bias[256 + ub + 1];
  float bG0 = bias[512 + ub], bG1 = bias[512 + ub + 1];
  float bO0 = bias[768 + ub], bO1 = bias[768 + ub + 1];

  // ---- prologue: stage x_0, acc = xg_0 ----
  {
    int ts = d ? (T_ - 1) : 0;
    const f32x4* px = (const f32x4*)(x + ((size_t)gb * T_ + ts) * E_ + sc * 8);
    float mk = mask[(size_t)gb * T_ + ts];
    ((short8*)XS)[sr * 32 + (sc ^ (sr & 7))] = cvt8(px[0] * mk, px[1] * mk);
  }
  __syncthreads();
  f32x4 acc[2] = {}, accB[2] = {};
#pragma unroll
  for (int kp = 0; kp < 4; ++kp) {
    short8 a0 = ((short8*)XS)[l15 * 32 + ((kp * 8 + l4) ^ (l15 & 7))];
    acc[0] = mfma16(a0, wi[0][2 * kp], acc[0]);
    acc[1] = mfma16(a0, wi[1][2 * kp], acc[1]);
    short8 a1 = ((short8*)XS)[l15 * 32 + ((kp * 8 + 4 + l4) ^ (l15 & 7))];
    accB[0] = mfma16(a1, wi[0][2 * kp + 1], accB[0]);
    accB[1] = mfma16(a1, wi[1][2 * kp + 1], accB[1]);
  }
  __syncthreads();  // XS consumed by all waves before loop overwrites it

  float cs0 = 0.f, cs1 = 0.f, hs0 = 0.f, hs1 = 0.f;

  for (int t = 0; t < T_; ++t) {
    // x prefetch for t+1: issued here, consumed ~3 phases later; never force-drained
    f32x4 xv0, xv1;
    float mk = 0.f;
    const bool more = (t + 1 < T_);
    if (more) {
      int ts = d ? (T_ - 2 - t) : (t + 1);
      const f32x4* px = (const f32x4*)(x + ((size_t)gb * T_ + ts) * E_ + sc * 8);
      xv0 = px[0];
      xv1 = px[1];
      mk = mask[(size_t)gb * T_ + ts];
    }

    // hh product into acc (acc holds xg_t)
    if (t > 0) {
#pragma unroll
      for (int kp = 0; kp < 4; ++kp) {
        short8 a0 = ((short8*)HS)[l15 * 32 + ((kp * 8 + l4) ^ (l15 & 7))];
        acc[0] = mfma16(a0, wh[0][2 * kp], acc[0]);
        acc[1] = mfma16(a0, wh[1][2 * kp], acc[1]);
        short8 a1 = ((short8*)HS)[l15 * 32 + ((kp * 8 + 4 + l4) ^ (l15 & 7))];
        accB[0] = mfma16(a1, wh[0][2 * kp + 1], accB[0]);
        accB[1] = mfma16(a1, wh[1][2 * kp + 1], accB[1]);
      }
    }

    // gates -> LDS. D layout: row(batch)=l4*4+r, col'=(2w+i)*16+l15
#pragma unroll
    for (int i = 0; i < 2; ++i)
#pragma unroll
      for (int r = 0; r < 4; ++r)
        gatesL[(l4 * 4 + r) * 260 + (2 * w + i) * 16 + l15] = acc[i][r] + accB[i][r];
    bar_lds();  // (1) gates visible

    // fp32 LSTM elementwise: 2 units (ej2, ej2+1), batch sr
    float gi0 = gatesL[sr * 260 + ej2] + bI0;
    float gf0 = gatesL[sr * 260 + 64 + ej2] + bF0;
    float gg0 = gatesL[sr * 260 + 128 + ej2] + bG0;
    float go0 = gatesL[sr * 260 + 192 + ej2] + bO0;
    float gi1 = gatesL[sr * 260 + ej2 + 1] + bI1;
    float gf1 = gatesL[sr * 260 + 64 + ej2 + 1] + bF1;
    float gg1 = gatesL[sr * 260 + 128 + ej2 + 1] + bG1;
    float go1 = gatesL[sr * 260 + 192 + ej2 + 1] + bO1;
    cs0 = sigmf(gf0) * cs0 + sigmf(gi0) * tanhfast(gg0);
    cs1 = sigmf(gf1) * cs1 + sigmf(gi1) * tanhfast(gg1);
    float h0 = sigmf(go0) * tanhfast(cs0);
    float h1 = sigmf(go1) * tanhfast(cs1);
    hs0 += h0;
    hs1 += h1;

    if (more) {
      const unsigned tag = (unsigned)(t + 1);
      const size_t base = ((size_t)g * 2 + (tag & 1)) * 16;  // [grp][parity][16b][128w]

      // publish own h slice ASAP (fire-and-forget; ack drains in background)
      unsigned payload = (unsigned)f2bf(h0) | ((unsigned)f2bf(h1) << 16);
      unsigned long long word = (((unsigned long long)tag) << 32) | payload;
      __hip_atomic_store(&Hbuf[(base + sr) * 128 + m * 32 + sc], word,
                         __ATOMIC_RELAXED, __HIP_MEMORY_SCOPE_AGENT);
      asm volatile("" ::: "memory");  // publish must not sink below the poll loop

      // poll-issue: first attempt overlaps XS stage + xg MFMA (free win if a peer
      // ran ahead; otherwise the parallel retry below pays exactly one more round)
      const unsigned long long* rp = &Hbuf[(base + sr) * 128 + sc * 4];
      unsigned long long vv[4];
#pragma unroll
      for (int j = 0; j < 4; ++j)
        vv[j] = __hip_atomic_load(&rp[j], __ATOMIC_RELAXED, __HIP_MEMORY_SCOPE_AGENT);
      asm volatile("" ::: "memory");

      // stage x_{t+1} (waits only this thread's x load)
      ((short8*)XS)[sr * 32 + (sc ^ (sr & 7))] = cvt8(xv0 * mk, xv1 * mk);
      bar_lds();  // (2) XS visible; gatesL fully read

      // acc = xg_{t+1}
      acc[0] = (f32x4){0.f, 0.f, 0.f, 0.f};
      acc[1] = (f32x4){0.f, 0.f, 0.f, 0.f};
      accB[0] = (f32x4){0.f, 0.f, 0.f, 0.f};
      accB[1] = (f32x4){0.f, 0.f, 0.f, 0.f};
#pragma unroll
      for (int kp = 0; kp < 4; ++kp) {
        short8 a0 = ((short8*)XS)[l15 * 32 + ((kp * 8 + l4) ^ (l15 & 7))];
        acc[0] = mfma16(a0, wi[0][2 * kp], acc[0]);
        acc[1] = mfma16(a0, wi[1][2 * kp], acc[1]);
        short8 a1 = ((short8*)XS)[l15 * 32 + ((kp * 8 + 4 + l4) ^ (l15 & 7))];
        accB[0] = mfma16(a1, wi[0][2 * kp + 1], accB[0]);
        accB[1] = mfma16(a1, wi[1][2 * kp + 1], accB[1]);
      }

      // poll-check: PARALLEL retry rounds — re-issue all stale words together,
      // one batched wait per round (1 L3 round trip, not 4 chained).
      for (;;) {
        bool ok = true;
#pragma unroll
        for (int j = 0; j < 4; ++j) ok &= ((unsigned)(vv[j] >> 32) == tag);
        if (ok) break;
#pragma unroll
        for (int j = 0; j < 4; ++j)
          if ((unsigned)(vv[j] >> 32) != tag)
            vv[j] = __hip_atomic_load(&rp[j], __ATOMIC_RELAXED, __HIP_MEMORY_SCOPE_AGENT);
        asm volatile("" ::: "memory");
      }
      short8 hv;
#pragma unroll
      for (int j = 0; j < 4; ++j) {
        hv[2 * j] = (short)(unsigned short)(vv[j] & 0xffffu);
        hv[2 * j + 1] = (short)(unsigned short)((vv[j] >> 16) & 0xffffu);
      }
      ((short8*)HS)[sr * 32 + (sc ^ (sr & 7))] = hv;
      bar_lds();  // (3) HS visible; XS fully read
    }
  }

  hsum[((size_t)d * B_ + gb) * H_ + ub] = hs0;
  hsum[((size_t)d * B_ + gb) * H_ + ub + 1] = hs1;
}

// ---------------- head: linear ----------------------------------------------
__global__ __launch_bounds__(256, 1) void head_kernel(
    const float* __restrict__ hsum, const float* __restrict__ Wlin,
    const float* __restrict__ blin, float* __restrict__ out) {
  int tid = threadIdx.x;  // 256 = 128 b x 2 c
  int b = tid >> 1, c = tid & 1;
  const f32x4* hf = (const f32x4*)(hsum + (size_t)b * H_);
  const f32x4* hbk = (const f32x4*)(hsum + (size_t)B_ * H_ + (size_t)b * H_);
  const f32x4* wl = (const f32x4*)(Wlin + (size_t)c * 512);
  float s = 0.f;
  for (int j = 0; j < 64; ++j) {
    f32x4 a = hf[j], ww = wl[j];
    s += a[0] * ww[0] + a[1] * ww[1] + a[2] * ww[2] + a[3] * ww[3];
  }
  for (int j = 0; j < 64; ++j) {
    f32x4 a = hbk[j], ww = wl[64 + j];
    s += a[0] * ww[0] + a[1] * ww[1] + a[2] * ww[2] + a[3] * ww[3];
  }
  out[tid] = s * (1.0f / 1024.0f) + blin[c];
}

// ---------------- launch -----------------------------------------------------
extern "C" void kernel_launch(void* const* d_in, const int* in_sizes, int n_in,
                              void* d_out, int out_size, void* d_ws, size_t ws_size,
                              hipStream_t stream) {
  const float* emb = (const float*)d_in[0];
  const float* mask = (const float*)d_in[1];
  const float* Wih_f = (const float*)d_in[2];
  const float* Whh_f = (const float*)d_in[3];
  const float* b_f = (const float*)d_in[4];
  const float* Wih_b = (const float*)d_in[5];
  const float* Whh_b = (const float*)d_in[6];
  const float* b_b = (const float*)d_in[7];
  const float* Wlin = (const float*)d_in[8];
  const float* blin = (const float*)d_in[9];
  float* out = (float*)d_out;

  // Hbuf: [16 groups][2 parity][16 batches][128 unit-pair words] x 8B = 512 KiB
  const size_t HBUF_BYTES = (size_t)16 * 2 * 16 * 128 * 8;
  const size_t HSUM_BYTES = (size_t)2 * B_ * H_ * 4;  // 256 KiB
  if (ws_size < HBUF_BYTES + HSUM_BYTES) return;

  char* ws = (char*)d_ws;
  unsigned long long* Hbuf = (unsigned long long*)ws;
  float* hsum = (float*)(ws + HBUF_BYTES);

  hipMemsetAsync(Hbuf, 0, HBUF_BYTES, stream);  // tags start at 1; replay-safe
  rec_kernel<<<64, 512, 0, stream>>>(emb, mask, Wih_f, Whh_f, b_f,
                                     Wih_b, Whh_b, b_b, Hbuf, hsum);
  head_kernel<<<1, 256, 0, stream>>>(hsum, Wlin, blin, out);
}